// Round 11
// baseline (197.662 us; speedup 1.0000x reference)
//
#include <hip/hip_runtime.h>
#include <math.h>

#define D 1024
#define S 8192
#define B 8
#define H 16
#define NROWS (B * S)
#define EPS_LN 1e-5f

typedef _Float16 h2 __attribute__((ext_vector_type(2)));
typedef __fp16 half8 __attribute__((ext_vector_type(8)));
typedef float f32x4 __attribute__((ext_vector_type(4)));

__device__ __forceinline__ float wred_sum(float v) {
#pragma unroll
  for (int m = 1; m < 64; m <<= 1) v += __shfl_xor(v, m, 64);
  return v;
}
__device__ __forceinline__ float wred_max(float v) {
#pragma unroll
  for (int m = 1; m < 64; m <<= 1) v = fmaxf(v, __shfl_xor(v, m, 64));
  return v;
}
__device__ __forceinline__ h2 pkh(float a, float b) {
#if __has_builtin(__builtin_amdgcn_cvt_pkrtz)
  return __builtin_bit_cast(h2, __builtin_amdgcn_cvt_pkrtz(a, b));
#else
  h2 r; r.x = (_Float16)a; r.y = (_Float16)b; return r;
#endif
}
__device__ __forceinline__ float fdot2(h2 a, h2 b, float c) {
#if __has_builtin(__builtin_amdgcn_fdot2)
  typedef __fp16 fp16v2 __attribute__((ext_vector_type(2)));
  return __builtin_amdgcn_fdot2(__builtin_bit_cast(fp16v2, a),
                                __builtin_bit_cast(fp16v2, b), c, false);
#else
  return c + (float)a.x * (float)b.x + (float)a.y * (float)b.y;
#endif
}
__device__ __forceinline__ h2 bch(unsigned int u) { return __builtin_bit_cast(h2, u); }
__device__ __forceinline__ unsigned int hbits(h2 v) {
  return __builtin_bit_cast(unsigned int, v);
}

// ---------- LN over one 1024-row per block (256 thr) ----------
__global__ void k_ln256(const float* __restrict__ in, const float* __restrict__ g,
                        const float* __restrict__ bb, float* __restrict__ out) {
  const int b = blockIdx.x, t = threadIdx.x;
  float4 v = ((const float4*)(in + (size_t)b * D))[t];
  float s = v.x + v.y + v.z + v.w;
  float s2 = fmaf(v.x, v.x, fmaf(v.y, v.y, fmaf(v.z, v.z, v.w * v.w)));
  __shared__ float red[8];
  float ws = wred_sum(s), ws2 = wred_sum(s2);
  const int lane = t & 63, wv = t >> 6;
  if (!lane) { red[wv] = ws; red[wv + 4] = ws2; }
  __syncthreads();
  ws = red[0] + red[1] + red[2] + red[3];
  ws2 = red[4] + red[5] + red[6] + red[7];
  const float m = ws * (1.f / D);
  const float rs = rsqrtf(ws2 * (1.f / D) - m * m + EPS_LN);
  const float4 gg = ((const float4*)g)[t], bv = ((const float4*)bb)[t];
  float4 o;
  o.x = (v.x - m) * rs * gg.x + bv.x;
  o.y = (v.y - m) * rs * gg.y + bv.y;
  o.z = (v.z - m) * rs * gg.z + bv.z;
  o.w = (v.w - m) * rs * gg.w + bv.w;
  ((float4*)(out + (size_t)b * D))[t] = o;
}

// ---------- fused: query LN (replicated per block) + q-projection ----------
__global__ void k_qln(const float* __restrict__ query, const float* __restrict__ ng,
                      const float* __restrict__ nb, const float* __restrict__ Wq,
                      const float* __restrict__ bq, float* __restrict__ qv) {
  __shared__ float qn[D];
  __shared__ float red[8];
  const int t = threadIdx.x, lane = t & 63, wv = t >> 6;
  float4 v = ((const float4*)query)[t];
  float s = v.x + v.y + v.z + v.w;
  float s2 = fmaf(v.x, v.x, fmaf(v.y, v.y, fmaf(v.z, v.z, v.w * v.w)));
  float ws = wred_sum(s), ws2 = wred_sum(s2);
  if (!lane) { red[wv] = ws; red[wv + 4] = ws2; }
  __syncthreads();
  ws = red[0] + red[1] + red[2] + red[3];
  ws2 = red[4] + red[5] + red[6] + red[7];
  const float m = ws * (1.f / D);
  const float rs = rsqrtf(ws2 * (1.f / D) - m * m + EPS_LN);
  const float4 gg = ((const float4*)ng)[t], bv = ((const float4*)nb)[t];
  float4 o;
  o.x = (v.x - m) * rs * gg.x + bv.x;
  o.y = (v.y - m) * rs * gg.y + bv.y;
  o.z = (v.z - m) * rs * gg.z + bv.z;
  o.w = (v.w - m) * rs * gg.w + bv.w;
  ((float4*)qn)[t] = o;
  __syncthreads();
  const int j = blockIdx.x * 4 + wv;
  const float4* wr = (const float4*)(Wq + (size_t)j * D);
  float acc = 0.f;
#pragma unroll
  for (int k = 0; k < 4; k++) {
    float4 a = ((const float4*)qn)[lane + 64 * k], w = wr[lane + 64 * k];
    acc = fmaf(a.x, w.x, acc); acc = fmaf(a.y, w.y, acc);
    acc = fmaf(a.z, w.z, acc); acc = fmaf(a.w, w.w, acc);
  }
  acc = wred_sum(acc);
  if (!lane) qv[j] = acc + bq[j];
}

// ---------- fused per-head: U-projection (LDS) + per-head consts + B1 fragments ----
__global__ void k_uprep(const float* __restrict__ qv, const float* __restrict__ Wk,
                        const float* __restrict__ g1, const float* __restrict__ b1,
                        const float* __restrict__ kgw, const float* __restrict__ kbw,
                        float* __restrict__ hc, uint4* __restrict__ B1) {
  __shared__ float sUf[D];
  __shared__ float qh[64];
  __shared__ float red[4][4];
  const int h = blockIdx.x, t = threadIdx.x;
  if (t < 64) qh[t] = qv[h * 64 + t];
  __syncthreads();
#pragma unroll
  for (int p = 0; p < 4; p++) {
    const int d = t + 256 * p;
    float acc = 0.f;
#pragma unroll 4
    for (int e = 0; e < 64; e++)
      acc = fmaf(qh[e], Wk[(size_t)(h * 64 + e) * D + d], acc);
    sUf[d] = acc * 0.125f;  // 1/sqrt(64)
  }
  __syncthreads();
  // per-head consts (c2..c5)
  {
    const float4 u = ((const float4*)sUf)[t];
    const float4 gv = ((const float4*)g1)[t], bv = ((const float4*)b1)[t];
    const float4 kgv = ((const float4*)kgw)[t], kbv = ((const float4*)kbw)[t];
    const float e0 = u.x * gv.x * kgv.x, e1 = u.y * gv.y * kgv.y;
    const float e2 = u.z * gv.z * kgv.z, e3 = u.w * gv.w * kgv.w;
    float p2 = u.x * kgv.x * bv.x + u.y * kgv.y * bv.y + u.z * kgv.z * bv.z +
               u.w * kgv.w * bv.w;
    float p3 = e0 + e1 + e2 + e3;
    float p4 = u.x * kgv.x + u.y * kgv.y + u.z * kgv.z + u.w * kgv.w;
    float p5 = u.x * kbv.x + u.y * kbv.y + u.z * kbv.z + u.w * kbv.w;
    p2 = wred_sum(p2); p3 = wred_sum(p3); p4 = wred_sum(p4); p5 = wred_sum(p5);
    const int lane = t & 63, wv = t >> 6;
    if (!lane) { red[wv][0] = p2; red[wv][1] = p3; red[wv][2] = p4; red[wv][3] = p5; }
  }
  __syncthreads();
  if (t < 4) {
    float a = red[0][t] + red[1][t] + red[2][t] + red[3][t];
    hc[t * 16 + h] = a;
  }
  // B1 fragments (col = h)
  if (t < 128) {
    const int grp = t;
    const int k0 = (grp >> 2) * 32 + (grp & 3) * 8;
    unsigned int w[4];
#pragma unroll
    for (int p = 0; p < 4; p++) {
      const int k = k0 + 2 * p;
      const float e0 = sUf[k] * g1[k] * kgw[k];
      const float e1 = sUf[k + 1] * g1[k + 1] * kgw[k + 1];
      w[p] = hbits(pkh(e0, e1));
    }
    B1[grp * 16 + h] = make_uint4(w[0], w[1], w[2], w[3]);
  }
}

// ---------- fused: 5 weight scalars + g/g^2/g*b fragment tables ----------
__global__ void k_prep0G(const float* __restrict__ g, const float* __restrict__ b,
                         float* __restrict__ sconst, uint4* __restrict__ gt,
                         uint4* __restrict__ g2t, uint4* __restrict__ gbt) {
  const int t = threadIdx.x;
  float4 gv = ((const float4*)g)[t], bv = ((const float4*)b)[t];
  float sg = gv.x + gv.y + gv.z + gv.w;
  float sb = bv.x + bv.y + bv.z + bv.w;
  float sbb = bv.x * bv.x + bv.y * bv.y + bv.z * bv.z + bv.w * bv.w;
  float sgb = gv.x * bv.x + gv.y * bv.y + gv.z * bv.z + gv.w * bv.w;
  float sgg = gv.x * gv.x + gv.y * gv.y + gv.z * gv.z + gv.w * gv.w;
  __shared__ float red[4][5];
  sg = wred_sum(sg); sb = wred_sum(sb); sbb = wred_sum(sbb);
  sgb = wred_sum(sgb); sgg = wred_sum(sgg);
  const int lane = t & 63, wv = t >> 6;
  if (!lane) { red[wv][0] = sg; red[wv][1] = sb; red[wv][2] = sbb; red[wv][3] = sgb; red[wv][4] = sgg; }
  __syncthreads();
  if (t < 5) {
    float a = red[0][t] + red[1][t] + red[2][t] + red[3][t];
    sconst[t] = a;
  }
  if (t < 128) {
    const int grp = t;
    const int k0 = (grp >> 2) * 32 + (grp & 3) * 8;
    unsigned int a[4], bb2[4], c[4];
#pragma unroll
    for (int p = 0; p < 4; p++) {
      const int k = k0 + 2 * p;
      const float g0 = g[k], g1v = g[k + 1];
      const float b0 = b[k], b1v = b[k + 1];
      a[p] = hbits(pkh(g0, g1v));
      bb2[p] = hbits(pkh(g0 * g0, g1v * g1v));
      c[p] = hbits(pkh(g0 * b0, g1v * b1v));
    }
    gt[grp] = make_uint4(a[0], a[1], a[2], a[3]);
    g2t[grp] = make_uint4(bb2[0], bb2[1], bb2[2], bb2[3]);
    gbt[grp] = make_uint4(c[0], c[1], c[2], c[3]);
  }
}

// ---------- pass 1 over x: MFMA head-dots + in-lane linear/square stats ----------
__global__ __launch_bounds__(256) void k_scores(
    const float* __restrict__ x, const uint4* __restrict__ B1,
    const uint4* __restrict__ gt, const uint4* __restrict__ g2t,
    const uint4* __restrict__ gbt,
    const float* __restrict__ hc, const float* __restrict__ sconst,
    float* __restrict__ stats, float* __restrict__ sc) {
  __shared__ __align__(16) uint4 sB[2048];                      // 32 KB
  __shared__ __align__(16) uint4 sg[128], sg2[128], sgb[128];   // 2 KB each
  for (int i = threadIdx.x; i < 2048; i += 256) sB[i] = B1[i];
  if (threadIdx.x < 128) {
    sg[threadIdx.x] = gt[threadIdx.x];
    sg2[threadIdx.x] = g2t[threadIdx.x];
    sgb[threadIdx.x] = gbt[threadIdx.x];
  }
  __syncthreads();
  const int lane = threadIdx.x & 63, wv = threadIdx.x >> 6;
  const int col = lane & 15, kg = lane >> 4;
  const int r0 = blockIdx.x * 64 + wv * 16;
  const float c2 = hc[col], c3 = hc[16 + col], c4 = hc[32 + col], c5 = hc[48 + col];
  const float Sg1 = sconst[0], Sb1 = sconst[1], Sbbc = sconst[2];
  const float Sgbc = sconst[3], Sggc = sconst[4];
  const h2 one = {(_Float16)1.f, (_Float16)1.f};
  const float* xrow = x + (size_t)(r0 + col) * D + kg * 8;
  f32x4 acc = {0.f, 0.f, 0.f, 0.f};
  float S0 = 0, S1 = 0, Sa = 0, Sb = 0, Sc = 0, Sd = 0;
#pragma unroll 2
  for (int ks = 0; ks < 32; ks++) {
    const float4 A0 = *(const float4*)(xrow + ks * 32);
    const float4 A1 = *(const float4*)(xrow + ks * 32 + 4);
    const h2 a0 = pkh(A0.x, A0.y), a1 = pkh(A0.z, A0.w);
    const h2 a2 = pkh(A1.x, A1.y), a3 = pkh(A1.z, A1.w);
    const uint4 bu = sB[(ks * 4 + kg) * 16 + col];
    const uint4 gu = sg[ks * 4 + kg];
    const uint4 g2u = sg2[ks * 4 + kg];
    const uint4 gbu = sgb[ks * 4 + kg];
    S0 = fdot2(a0, one, S0); S0 = fdot2(a1, one, S0);
    S0 = fdot2(a2, one, S0); S0 = fdot2(a3, one, S0);
    S1 = fdot2(a0, a0, S1); S1 = fdot2(a1, a1, S1);
    S1 = fdot2(a2, a2, S1); S1 = fdot2(a3, a3, S1);
    const h2 g0 = bch(gu.x), g1p = bch(gu.y), g2p = bch(gu.z), g3p = bch(gu.w);
    Sa = fdot2(g0, a0, Sa); Sa = fdot2(g1p, a1, Sa);
    Sa = fdot2(g2p, a2, Sa); Sa = fdot2(g3p, a3, Sa);
    const h2 G0 = bch(g2u.x), G1 = bch(g2u.y), G2 = bch(g2u.z), G3 = bch(g2u.w);
    Sb = fdot2(G0, a0, Sb); Sb = fdot2(G1, a1, Sb);
    Sb = fdot2(G2, a2, Sb); Sb = fdot2(G3, a3, Sb);
    Sc = fdot2(G0, a0 * a0, Sc); Sc = fdot2(G1, a1 * a1, Sc);
    Sc = fdot2(G2, a2 * a2, Sc); Sc = fdot2(G3, a3 * a3, Sc);
    const h2 Q0 = bch(gbu.x), Q1 = bch(gbu.y), Q2 = bch(gbu.z), Q3 = bch(gbu.w);
    Sd = fdot2(Q0, a0, Sd); Sd = fdot2(Q1, a1, Sd);
    Sd = fdot2(Q2, a2, Sd); Sd = fdot2(Q3, a3, Sd);
    union { h2 p[4]; half8 v; } ua;
    ua.p[0] = a0; ua.p[1] = a1; ua.p[2] = a2; ua.p[3] = a3;
    const half8 bf = __builtin_bit_cast(half8, bu);
    acc = __builtin_amdgcn_mfma_f32_16x16x32_f16(ua.v, bf, acc, 0, 0, 0);
  }
#pragma unroll
  for (int m = 16; m < 64; m <<= 1) {
    S0 += __shfl_xor(S0, m, 64); S1 += __shfl_xor(S1, m, 64);
    Sa += __shfl_xor(Sa, m, 64); Sb += __shfl_xor(Sb, m, 64);
    Sc += __shfl_xor(Sc, m, 64); Sd += __shfl_xor(Sd, m, 64);
  }
  const float m1 = S0 * (1.f / D);
  const float rs1 = rsqrtf(S1 * (1.f / D) - m1 * m1 + EPS_LN);
  const float m2 = (rs1 * (Sa - m1 * Sg1) + Sb1) * (1.f / D);
  const float sxn2 = rs1 * rs1 * Sc + 2.f * rs1 * (Sd - m1 * rs1 * Sb) +
                     (Sbbc - 2.f * m1 * rs1 * Sgbc + m1 * m1 * rs1 * rs1 * Sggc);
  const float rs2 = rsqrtf(sxn2 * (1.f / D) - m2 * m2 + EPS_LN);
  if (lane < 16) ((float4*)stats)[r0 + col] = make_float4(m1, rs1, m2, rs2);
  const float v1 = rs1 * rs2, v2 = v1 * m1, v3 = rs2, v4 = rs2 * m2;
#pragma unroll
  for (int reg = 0; reg < 4; reg++) {
    const int rrow = kg * 4 + reg;
    const float w1 = __shfl(v1, rrow, 64);
    const float w2 = __shfl(v2, rrow, 64);
    const float w3 = __shfl(v3, rrow, 64);
    const float w4 = __shfl(v4, rrow, 64);
    sc[(size_t)(r0 + rrow) * 16 + col] =
        w1 * acc[reg] - w2 * c3 + w3 * c2 - w4 * c4 + c5;
  }
}

// ---------- softmax stage 1: per-chunk max + sum(exp(v-max)) ----------
__global__ void k_smax1(const float* __restrict__ sc, float* __restrict__ pmax,
                        float* __restrict__ psum) {
  const int blk = blockIdx.x, t = threadIdx.x;
  const int b = blk >> 4, c = blk & 15;
  const int r0 = b * S + c * 512;
  __shared__ float lM[4][16], lS[4][16];
  float mx[16];
#pragma unroll
  for (int h = 0; h < 16; h++) mx[h] = -3.4e38f;
#pragma unroll
  for (int rr = 0; rr < 2; rr++) {
    const float4* row = (const float4*)(sc + (size_t)(r0 + t + 256 * rr) * 16);
    const float4 v0 = row[0], v1 = row[1], v2 = row[2], v3 = row[3];
    mx[0] = fmaxf(mx[0], v0.x); mx[1] = fmaxf(mx[1], v0.y);
    mx[2] = fmaxf(mx[2], v0.z); mx[3] = fmaxf(mx[3], v0.w);
    mx[4] = fmaxf(mx[4], v1.x); mx[5] = fmaxf(mx[5], v1.y);
    mx[6] = fmaxf(mx[6], v1.z); mx[7] = fmaxf(mx[7], v1.w);
    mx[8] = fmaxf(mx[8], v2.x); mx[9] = fmaxf(mx[9], v2.y);
    mx[10] = fmaxf(mx[10], v2.z); mx[11] = fmaxf(mx[11], v2.w);
    mx[12] = fmaxf(mx[12], v3.x); mx[13] = fmaxf(mx[13], v3.y);
    mx[14] = fmaxf(mx[14], v3.z); mx[15] = fmaxf(mx[15], v3.w);
  }
  const int lane = t & 63, wv = t >> 6;
#pragma unroll
  for (int h = 0; h < 16; h++) mx[h] = wred_max(mx[h]);
  if (!lane) {
#pragma unroll
    for (int h = 0; h < 16; h++) lM[wv][h] = mx[h];
  }
  __syncthreads();
  float M[16];
#pragma unroll
  for (int h = 0; h < 16; h++)
    M[h] = fmaxf(fmaxf(lM[0][h], lM[1][h]), fmaxf(lM[2][h], lM[3][h]));
  float sm[16];
#pragma unroll
  for (int h = 0; h < 16; h++) sm[h] = 0.f;
#pragma unroll
  for (int rr = 0; rr < 2; rr++) {
    const float4* row = (const float4*)(sc + (size_t)(r0 + t + 256 * rr) * 16);
    const float4 v0 = row[0], v1 = row[1], v2 = row[2], v3 = row[3];
    sm[0] += __expf(v0.x - M[0]); sm[1] += __expf(v0.y - M[1]);
    sm[2] += __expf(v0.z - M[2]); sm[3] += __expf(v0.w - M[3]);
    sm[4] += __expf(v1.x - M[4]); sm[5] += __expf(v1.y - M[5]);
    sm[6] += __expf(v1.z - M[6]); sm[7] += __expf(v1.w - M[7]);
    sm[8] += __expf(v2.x - M[8]); sm[9] += __expf(v2.y - M[9]);
    sm[10] += __expf(v2.z - M[10]); sm[11] += __expf(v2.w - M[11]);
    sm[12] += __expf(v3.x - M[12]); sm[13] += __expf(v3.y - M[13]);
    sm[14] += __expf(v3.z - M[14]); sm[15] += __expf(v3.w - M[15]);
  }
#pragma unroll
  for (int h = 0; h < 16; h++) sm[h] = wred_sum(sm[h]);
  if (!lane) {
#pragma unroll
    for (int h = 0; h < 16; h++) lS[wv][h] = sm[h];
  }
  __syncthreads();
  if (t < 16) {
    float m = fmaxf(fmaxf(lM[0][t], lM[1][t]), fmaxf(lM[2][t], lM[3][t]));
    float s = lS[0][t] + lS[1][t] + lS[2][t] + lS[3][t];
    pmax[blk * 16 + t] = m;
    psum[blk * 16 + t] = s;
  }
}

// ---------- softmax stage 2: combine 16 chunks per (b,h); zero Cbuf ----------
__global__ void k_smax2(const float* __restrict__ pmax, const float* __restrict__ psum,
                        float* __restrict__ gmax, float* __restrict__ ginv,
                        float* __restrict__ Cbuf) {
  const int t = threadIdx.x;  // 128 = B*H
  const int b = t >> 4, h = t & 15;
  float M = -3.4e38f;
  for (int c = 0; c < 16; c++) M = fmaxf(M, pmax[(b * 16 + c) * 16 + h]);
  float sum = 0.f;
  for (int c = 0; c < 16; c++)
    sum += psum[(b * 16 + c) * 16 + h] * __expf(pmax[(b * 16 + c) * 16 + h] - M);
  gmax[t] = M;
  ginv[t] = 1.f / (sum + 1e-9f);
  ((float4*)Cbuf)[t] = make_float4(0.f, 0.f, 0.f, 0.f);
}

// ---------- softmax stage 3: materialize w' = clip(w)*rs12; reduce C0..C3 ----------
__global__ void k_smax3(float* __restrict__ sc, const float* __restrict__ gmax,
                        const float* __restrict__ ginv, const float* __restrict__ stats,
                        float* __restrict__ Cbuf) {
  const int r = blockIdx.x * 256 + threadIdx.x;
  const int b = r >> 13;
  const int t = threadIdx.x, lane = t & 63, wv = t >> 6;
  __shared__ float lC[4][16][4];
  float4 M[4], I[4];
#pragma unroll
  for (int k = 0; k < 4; k++) {
    M[k] = ((const float4*)(gmax + b * 16))[k];
    I[k] = ((const float4*)(ginv + b * 16))[k];
  }
  const float4 st = ((const float4*)stats)[r];  // m1 rs1 m2 rs2
  const float rs12 = st.y * st.w;
  float w[16];
  float4* row = (float4*)(sc + (size_t)r * 16);
#pragma unroll
  for (int k = 0; k < 4; k++) {
    float4 v = row[k];
    w[4 * k + 0] = fminf(fmaxf(__expf(v.x - M[k].x) * I[k].x, 1e-9f), 1.f);
    w[4 * k + 1] = fminf(fmaxf(__expf(v.y - M[k].y) * I[k].y, 1e-9f), 1.f);
    w[4 * k + 2] = fminf(fmaxf(__expf(v.z - M[k].z) * I[k].z, 1e-9f), 1.f);
    w[4 * k + 3] = fminf(fmaxf(__expf(v.w - M[k].w) * I[k].w, 1e-9f), 1.f);
    v.x = w[4 * k + 0] * rs12; v.y = w[4 * k + 1] * rs12;
    v.z = w[4 * k + 2] * rs12; v.w = w[4 * k + 3] * rs12;
    row[k] = v;
  }
  // per-head partial sums: C0=Σw, C1=Σw·rs2, C2=Σw·rs12·m1, C3=Σw·rs2·m2
  const float f1 = st.w, f2 = rs12 * st.x, f3 = st.w * st.z;
#pragma unroll
  for (int h = 0; h < 16; h++) {
    float c0 = wred_sum(w[h]);
    float c1 = wred_sum(w[h] * f1);
    float c2 = wred_sum(w[h] * f2);
    float c3 = wred_sum(w[h] * f3);
    if (!lane) { lC[wv][h][0] = c0; lC[wv][h][1] = c1; lC[wv][h][2] = c2; lC[wv][h][3] = c3; }
  }
  __syncthreads();
  if (t < 64) {
    const int h = t >> 2, c = t & 3;
    const float v = lC[0][h][c] + lC[1][h][c] + lC[2][h][c] + lC[3][h][c];
    atomicAdd(&Cbuf[(b * 16 + h) * 4 + c], v);
  }
}

// ---------- pass 2 over x: pure weighted raw-x accumulate (T1 partials) ----------
__global__ __launch_bounds__(512) void k_accv(
    const float* __restrict__ x, const float* __restrict__ attn,
    float* __restrict__ part, int CH, int RPC) {
  const int b = blockIdx.x / CH, ch = blockIdx.x % CH;
  const int c0 = threadIdx.x * 2;
  float acc0[16], acc1[16];
#pragma unroll
  for (int h = 0; h < 16; h++) { acc0[h] = 0.f; acc1[h] = 0.f; }
  const int r0 = b * S + ch * RPC;
#pragma unroll 2
  for (int i = 0; i < RPC; i++) {
    const int r = r0 + i;
    const float2 xv = *(const float2*)(x + (size_t)r * D + c0);
    const float4* wr = (const float4*)(attn + (size_t)r * 16);
    const float4 w0 = wr[0], w1 = wr[1], w2 = wr[2], w3 = wr[3];
    const float v0 = xv.x, v1 = xv.y;
    acc0[0] = fmaf(w0.x, v0, acc0[0]);   acc1[0] = fmaf(w0.x, v1, acc1[0]);
    acc0[1] = fmaf(w0.y, v0, acc0[1]);   acc1[1] = fmaf(w0.y, v1, acc1[1]);
    acc0[2] = fmaf(w0.z, v0, acc0[2]);   acc1[2] = fmaf(w0.z, v1, acc1[2]);
    acc0[3] = fmaf(w0.w, v0, acc0[3]);   acc1[3] = fmaf(w0.w, v1, acc1[3]);
    acc0[4] = fmaf(w1.x, v0, acc0[4]);   acc1[4] = fmaf(w1.x, v1, acc1[4]);
    acc0[5] = fmaf(w1.y, v0, acc0[5]);   acc1[5] = fmaf(w1.y, v1, acc1[5]);
    acc0[6] = fmaf(w1.z, v0, acc0[6]);   acc1[6] = fmaf(w1.z, v1, acc1[6]);
    acc0[7] = fmaf(w1.w, v0, acc0[7]);   acc1[7] = fmaf(w1.w, v1, acc1[7]);
    acc0[8] = fmaf(w2.x, v0, acc0[8]);   acc1[8] = fmaf(w2.x, v1, acc1[8]);
    acc0[9] = fmaf(w2.y, v0, acc0[9]);   acc1[9] = fmaf(w2.y, v1, acc1[9]);
    acc0[10] = fmaf(w2.z, v0, acc0[10]); acc1[10] = fmaf(w2.z, v1, acc1[10]);
    acc0[11] = fmaf(w2.w, v0, acc0[11]); acc1[11] = fmaf(w2.w, v1, acc1[11]);
    acc0[12] = fmaf(w3.x, v0, acc0[12]); acc1[12] = fmaf(w3.x, v1, acc1[12]);
    acc0[13] = fmaf(w3.y, v0, acc0[13]); acc1[13] = fmaf(w3.y, v1, acc1[13]);
    acc0[14] = fmaf(w3.z, v0, acc0[14]); acc1[14] = fmaf(w3.z, v1, acc1[14]);
    acc0[15] = fmaf(w3.w, v0, acc0[15]); acc1[15] = fmaf(w3.w, v1, acc1[15]);
  }
  float* po = part + (size_t)blockIdx.x * (H * D);
#pragma unroll
  for (int h = 0; h < 16; h++)
    *(float2*)(po + h * D + c0) = make_float2(acc0[h], acc1[h]);
}

// ---------- reduce chunk partials + assemble pooled v via affine consts ----------
__global__ void k_redpart(const float* __restrict__ part, const float* __restrict__ Cbuf,
                          const float* __restrict__ g1, const float* __restrict__ b1,
                          const float* __restrict__ vg, const float* __restrict__ vb,
                          float* __restrict__ vpool, int CH) {
  const int b = blockIdx.x >> 4, h = blockIdx.x & 15;
  const int t = threadIdx.x, d = t * 4;
  float4 a = make_float4(0.f, 0.f, 0.f, 0.f);
  for (int k = 0; k < CH; k++) {
    const float4 p = *(const float4*)(part + ((size_t)(b * CH + k) * H + h) * D + d);
    a.x += p.x; a.y += p.y; a.z += p.z; a.w += p.w;
  }
  const float4 C = ((const float4*)Cbuf)[b * 16 + h];  // C0 C1 C2 C3
  const float4 gv = ((const float4*)g1)[t], bv = ((const float4*)b1)[t];
  const float4 vgv = ((const float4*)vg)[t], vbv = ((const float4*)vb)[t];
  float4 o;
  o.x = vgv.x * (gv.x * (a.x - C.z) + bv.x * C.y - C.w) + vbv.x * C.x;
  o.y = vgv.y * (gv.y * (a.y - C.z) + bv.y * C.y - C.w) + vbv.y * C.x;
  o.z = vgv.z * (gv.z * (a.z - C.z) + bv.z * C.y - C.w) + vbv.z * C.x;
  o.w = vgv.w * (gv.w * (a.w - C.z) + bv.w * C.y - C.w) + vbv.w * C.x;
  *(float4*)(vpool + ((size_t)b * H + h) * D + d) = o;
}

// ---------- out[b][j] = W[j,:] . src[b, (maybe head-sliced)] + bias[j] ----------
__global__ void k_proj8(const float* __restrict__ src, const float* __restrict__ W,
                        const float* __restrict__ bias, float* __restrict__ out,
                        int bstride, int hstride) {
  const int j = blockIdx.x, lane = threadIdx.x;
  const int h = j >> 6;
  const float4* wr = (const float4*)(W + (size_t)j * D);
  float acc[8];
#pragma unroll
  for (int b = 0; b < 8; b++) acc[b] = 0.f;
#pragma unroll
  for (int k = 0; k < 4; k++) {
    const float4 w4 = wr[lane + 64 * k];
#pragma unroll
    for (int b = 0; b < 8; b++) {
      const float4 s4 =
          ((const float4*)(src + (size_t)b * bstride + (size_t)h * hstride))[lane + 64 * k];
      acc[b] = fmaf(w4.x, s4.x, acc[b]); acc[b] = fmaf(w4.y, s4.y, acc[b]);
      acc[b] = fmaf(w4.z, s4.z, acc[b]); acc[b] = fmaf(w4.w, s4.w, acc[b]);
    }
  }
#pragma unroll
  for (int b = 0; b < 8; b++) acc[b] = wred_sum(acc[b]);
  if (!lane) {
    const float bj = bias[j];
#pragma unroll
    for (int b = 0; b < 8; b++) out[(size_t)b * D + j] = acc[b] + bj;
  }
}

extern "C" void kernel_launch(void* const* d_in, const int* in_sizes, int n_in,
                              void* d_out, int out_size, void* d_ws, size_t ws_size,
                              hipStream_t stream) {
  const float* x = (const float*)d_in[0];
  const float* query = (const float*)d_in[1];
  const float* norm_g = (const float*)d_in[2];
  const float* norm_b = (const float*)d_in[3];
  const float* nq_g = (const float*)d_in[4];
  const float* nq_b = (const float*)d_in[5];
  const float* nk_g = (const float*)d_in[6];
  const float* nk_b = (const float*)d_in[7];
  const float* nv_g = (const float*)d_in[8];
  const float* nv_b = (const float*)d_in[9];
  const float* no_g = (const float*)d_in[10];
  const float* no_b = (const float*)d_in[11];
  const float* Wq = (const float*)d_in[12];
  const float* bq = (const float*)d_in[13];
  const float* Wk = (const float*)d_in[14];
  // d_in[15] = bk: constant per (b,h) in scores -> cancels in softmax
  const float* Wv = (const float*)d_in[16];
  const float* bv = (const float*)d_in[17];
  const float* Wo = (const float*)d_in[18];
  const float* bo = (const float*)d_in[19];

  char* ws = (char*)d_ws;
  float* qv = (float*)(ws + 0);            // 4 KB
  uint4* B1 = (uint4*)(ws + 4096);         // 32 KB
  uint4* gt = (uint4*)(ws + 36864);        // 2 KB
  uint4* g2t = (uint4*)(ws + 38912);       // 2 KB
  uint4* gbt = (uint4*)(ws + 40960);       // 2 KB
  float* hc = (float*)(ws + 43008);        // 256 B
  float* sconst = (float*)(ws + 43264);    // 64 B
  float* gmax = (float*)(ws + 43328);      // 512 B
  float* ginv = (float*)(ws + 43840);      // 512 B
  float* Cbuf = (float*)(ws + 44352);      // 2 KB
  float* pmax = (float*)(ws + 46400);      // 8 KB
  float* psum = (float*)(ws + 54592);      // 8 KB
  float* stats = (float*)(ws + 62784);     // 1 MB
  float* sc = (float*)(ws + 1111360);      // 4 MB
  float* vpool = (float*)(ws + 5305664);   // 512 KB
  float* av = (float*)(ws + 5829952);      // 32 KB
  float* yb = (float*)(ws + 5862720);      // 32 KB
  float* part = (float*)(ws + 5895488);    // B*CH*H*D*4

  int CH = 64;
  while (CH > 1 && 5895488ull + (size_t)B * CH * H * D * 4 > ws_size) CH >>= 1;
  const int RPC = S / CH;

  k_qln<<<256, 256, 0, stream>>>(query, nq_g, nq_b, Wq, bq, qv);
  k_prep0G<<<1, 256, 0, stream>>>(norm_g, norm_b, sconst, gt, g2t, gbt);
  k_uprep<<<16, 256, 0, stream>>>(qv, Wk, norm_g, norm_b, nk_g, nk_b, hc, B1);
  k_scores<<<NROWS / 64, 256, 0, stream>>>(x, B1, gt, g2t, gbt, hc, sconst, stats, sc);
  k_smax1<<<128, 256, 0, stream>>>(sc, pmax, psum);
  k_smax2<<<1, 128, 0, stream>>>(pmax, psum, gmax, ginv, Cbuf);
  k_smax3<<<256, 256, 0, stream>>>(sc, gmax, ginv, stats, Cbuf);
  k_accv<<<B * CH, 512, 0, stream>>>(x, sc, part, CH, RPC);
  k_redpart<<<128, 256, 0, stream>>>(part, Cbuf, norm_g, norm_b, nv_g, nv_b, vpool, CH);
  k_proj8<<<1024, 64, 0, stream>>>(vpool, Wv, bv, av, H * D, D);  // V-proj on pooled
  k_proj8<<<1024, 64, 0, stream>>>(av, Wo, bo, yb, D, 0);         // O-proj
  k_ln256<<<8, 256, 0, stream>>>(yb, no_g, no_b, (float*)d_out);
}

// Round 12
// 114.004 us; speedup vs baseline: 1.7338x; 1.7338x over previous
//
#include <hip/hip_runtime.h>
#include <math.h>

#define D 1024
#define S 8192
#define B 8
#define H 16
#define NROWS (B * S)
#define EPS_LN 1e-5f

typedef _Float16 h2 __attribute__((ext_vector_type(2)));
typedef __fp16 half8 __attribute__((ext_vector_type(8)));
typedef float f32x4 __attribute__((ext_vector_type(4)));

__device__ __forceinline__ float wred_sum(float v) {
#pragma unroll
  for (int m = 1; m < 64; m <<= 1) v += __shfl_xor(v, m, 64);
  return v;
}
__device__ __forceinline__ h2 pkh(float a, float b) {
#if __has_builtin(__builtin_amdgcn_cvt_pkrtz)
  return __builtin_bit_cast(h2, __builtin_amdgcn_cvt_pkrtz(a, b));
#else
  h2 r; r.x = (_Float16)a; r.y = (_Float16)b; return r;
#endif
}
__device__ __forceinline__ float fdot2(h2 a, h2 b, float c) {
#if __has_builtin(__builtin_amdgcn_fdot2)
  typedef __fp16 fp16v2 __attribute__((ext_vector_type(2)));
  return __builtin_amdgcn_fdot2(__builtin_bit_cast(fp16v2, a),
                                __builtin_bit_cast(fp16v2, b), c, false);
#else
  return c + (float)a.x * (float)b.x + (float)a.y * (float)b.y;
#endif
}
__device__ __forceinline__ h2 bch(unsigned int u) { return __builtin_bit_cast(h2, u); }
__device__ __forceinline__ unsigned int hbits(h2 v) {
  return __builtin_bit_cast(unsigned int, v);
}

// ---------- LN over one 1024-row per block (256 thr) ----------
__global__ void k_ln256(const float* __restrict__ in, const float* __restrict__ g,
                        const float* __restrict__ bb, float* __restrict__ out) {
  const int b = blockIdx.x, t = threadIdx.x;
  float4 v = ((const float4*)(in + (size_t)b * D))[t];
  float s = v.x + v.y + v.z + v.w;
  float s2 = fmaf(v.x, v.x, fmaf(v.y, v.y, fmaf(v.z, v.z, v.w * v.w)));
  __shared__ float red[8];
  float ws = wred_sum(s), ws2 = wred_sum(s2);
  const int lane = t & 63, wv = t >> 6;
  if (!lane) { red[wv] = ws; red[wv + 4] = ws2; }
  __syncthreads();
  ws = red[0] + red[1] + red[2] + red[3];
  ws2 = red[4] + red[5] + red[6] + red[7];
  const float m = ws * (1.f / D);
  const float rs = rsqrtf(ws2 * (1.f / D) - m * m + EPS_LN);
  const float4 gg = ((const float4*)g)[t], bv = ((const float4*)bb)[t];
  float4 o;
  o.x = (v.x - m) * rs * gg.x + bv.x;
  o.y = (v.y - m) * rs * gg.y + bv.y;
  o.z = (v.z - m) * rs * gg.z + bv.z;
  o.w = (v.w - m) * rs * gg.w + bv.w;
  ((float4*)(out + (size_t)b * D))[t] = o;
}

// ---------- fused: query LN (replicated) + q-projection ----------
__global__ void k_qln(const float* __restrict__ query, const float* __restrict__ ng,
                      const float* __restrict__ nb, const float* __restrict__ Wq,
                      const float* __restrict__ bq, float* __restrict__ qv) {
  __shared__ float qn[D];
  __shared__ float red[8];
  const int t = threadIdx.x, lane = t & 63, wv = t >> 6;
  float4 v = ((const float4*)query)[t];
  float s = v.x + v.y + v.z + v.w;
  float s2 = fmaf(v.x, v.x, fmaf(v.y, v.y, fmaf(v.z, v.z, v.w * v.w)));
  float ws = wred_sum(s), ws2 = wred_sum(s2);
  if (!lane) { red[wv] = ws; red[wv + 4] = ws2; }
  __syncthreads();
  ws = red[0] + red[1] + red[2] + red[3];
  ws2 = red[4] + red[5] + red[6] + red[7];
  const float m = ws * (1.f / D);
  const float rs = rsqrtf(ws2 * (1.f / D) - m * m + EPS_LN);
  const float4 gg = ((const float4*)ng)[t], bv = ((const float4*)nb)[t];
  float4 o;
  o.x = (v.x - m) * rs * gg.x + bv.x;
  o.y = (v.y - m) * rs * gg.y + bv.y;
  o.z = (v.z - m) * rs * gg.z + bv.z;
  o.w = (v.w - m) * rs * gg.w + bv.w;
  ((float4*)qn)[t] = o;
  __syncthreads();
  const int j = blockIdx.x * 4 + wv;
  const float4* wr = (const float4*)(Wq + (size_t)j * D);
  float acc = 0.f;
#pragma unroll
  for (int k = 0; k < 4; k++) {
    float4 a = ((const float4*)qn)[lane + 64 * k], w = wr[lane + 64 * k];
    acc = fmaf(a.x, w.x, acc); acc = fmaf(a.y, w.y, acc);
    acc = fmaf(a.z, w.z, acc); acc = fmaf(a.w, w.w, acc);
  }
  acc = wred_sum(acc);
  if (!lane) qv[j] = acc + bq[j];
}

// ---------- fused: weight scalars + g-tables + zero hc/Cbuf ----------
__global__ void k_prep0G(const float* __restrict__ g, const float* __restrict__ b,
                         float* __restrict__ sconst, uint4* __restrict__ gt,
                         uint4* __restrict__ g2t, uint4* __restrict__ gbt,
                         float* __restrict__ hc, float* __restrict__ Cbuf) {
  const int t = threadIdx.x;
  float4 gv = ((const float4*)g)[t], bv = ((const float4*)b)[t];
  float sg = gv.x + gv.y + gv.z + gv.w;
  float sb = bv.x + bv.y + bv.z + bv.w;
  float sbb = bv.x * bv.x + bv.y * bv.y + bv.z * bv.z + bv.w * bv.w;
  float sgb = gv.x * bv.x + gv.y * bv.y + gv.z * bv.z + gv.w * bv.w;
  float sgg = gv.x * gv.x + gv.y * gv.y + gv.z * gv.z + gv.w * gv.w;
  __shared__ float red[4][5];
  sg = wred_sum(sg); sb = wred_sum(sb); sbb = wred_sum(sbb);
  sgb = wred_sum(sgb); sgg = wred_sum(sgg);
  const int lane = t & 63, wv = t >> 6;
  if (!lane) { red[wv][0] = sg; red[wv][1] = sb; red[wv][2] = sbb; red[wv][3] = sgb; red[wv][4] = sgg; }
  __syncthreads();
  if (t < 5) sconst[t] = red[0][t] + red[1][t] + red[2][t] + red[3][t];
  if (t < 16) ((float4*)hc)[t] = make_float4(0.f, 0.f, 0.f, 0.f);
  if (t < 128) ((float4*)Cbuf)[t] = make_float4(0.f, 0.f, 0.f, 0.f);
  if (t < 128) {
    const int grp = t;
    const int k0 = (grp >> 2) * 32 + (grp & 3) * 8;
    unsigned int a[4], bb2[4], c[4];
#pragma unroll
    for (int p = 0; p < 4; p++) {
      const int k = k0 + 2 * p;
      const float g0 = g[k], g1v = g[k + 1];
      const float b0 = b[k], b1v = b[k + 1];
      a[p] = hbits(pkh(g0, g1v));
      bb2[p] = hbits(pkh(g0 * g0, g1v * g1v));
      c[p] = hbits(pkh(g0 * b0, g1v * b1v));
    }
    gt[grp] = make_uint4(a[0], a[1], a[2], a[3]);
    g2t[grp] = make_uint4(bb2[0], bb2[1], bb2[2], bb2[3]);
    gbt[grp] = make_uint4(c[0], c[1], c[2], c[3]);
  }
}

// ---------- per (head, quarter): U-proj slice + hc partials (atomic) + B1 frags ----
__global__ void k_uprep64(const float* __restrict__ qv, const float* __restrict__ Wk,
                          const float* __restrict__ g1, const float* __restrict__ b1,
                          const float* __restrict__ kgw, const float* __restrict__ kbw,
                          float* __restrict__ hc, uint4* __restrict__ B1) {
  __shared__ float sUf[256];
  __shared__ float qh[64];
  __shared__ float red[4][4];
  const int h = blockIdx.x >> 2, q = blockIdx.x & 3, t = threadIdx.x;
  if (t < 64) qh[t] = qv[h * 64 + t];
  __syncthreads();
  const int d = q * 256 + t;
  float acc = 0.f;
#pragma unroll 4
  for (int e = 0; e < 64; e++)
    acc = fmaf(qh[e], Wk[(size_t)(h * 64 + e) * D + d], acc);
  acc *= 0.125f;  // 1/sqrt(64)
  sUf[t] = acc;
  const float gv = g1[d], bv = b1[d], kgv = kgw[d], kbv = kbw[d];
  float p2 = acc * kgv * bv;
  float p3 = acc * gv * kgv;
  float p4 = acc * kgv;
  float p5 = acc * kbv;
  p2 = wred_sum(p2); p3 = wred_sum(p3); p4 = wred_sum(p4); p5 = wred_sum(p5);
  const int lane = t & 63, wv = t >> 6;
  if (!lane) { red[wv][0] = p2; red[wv][1] = p3; red[wv][2] = p4; red[wv][3] = p5; }
  __syncthreads();
  if (t < 4)
    atomicAdd(&hc[t * 16 + h], red[0][t] + red[1][t] + red[2][t] + red[3][t]);
  if (t < 32) {
    const int grp = q * 32 + t;
    const int k0 = (grp >> 2) * 32 + (grp & 3) * 8;  // global dim base
    const int kl = k0 - q * 256;                      // local 0..255
    unsigned int wv2[4];
#pragma unroll
    for (int p = 0; p < 4; p++) {
      const int k = kl + 2 * p, kg2 = k0 + 2 * p;
      const float e0 = sUf[k] * g1[kg2] * kgw[kg2];
      const float e1 = sUf[k + 1] * g1[kg2 + 1] * kgw[kg2 + 1];
      wv2[p] = hbits(pkh(e0, e1));
    }
    B1[grp * 16 + h] = make_uint4(wv2[0], wv2[1], wv2[2], wv2[3]);
  }
}

// ---------- SINGLE PASS over x: scores (MFMA) + stats + online exp + PV (MFMA) ----
__global__ __launch_bounds__(256) void k_fused(
    const float* __restrict__ x, const uint4* __restrict__ B1,
    const uint4* __restrict__ gt, const uint4* __restrict__ g2t,
    const uint4* __restrict__ gbt, const float* __restrict__ hc,
    const float* __restrict__ sconst, float* __restrict__ part,
    float* __restrict__ Cbuf, int niter, int bpb) {
  __shared__ __align__(16) uint4 sB[2048];                     // 32 KB
  __shared__ __align__(16) uint4 sg[128], sg2[128], sgb[128];  // 6 KB
  __shared__ __align__(16) unsigned int xl[4][16 * 133];       // 34 KB (x f16 tiles)
  __shared__ __align__(16) f32x4 sred[4][64];                  // 4 KB
  __shared__ float stat[4][16][6];                             // 1.5 KB
  for (int i = threadIdx.x; i < 2048; i += 256) sB[i] = B1[i];
  if (threadIdx.x < 128) {
    sg[threadIdx.x] = gt[threadIdx.x];
    sg2[threadIdx.x] = g2t[threadIdx.x];
    sgb[threadIdx.x] = gbt[threadIdx.x];
  }
  __syncthreads();
  const int lane = threadIdx.x & 63, w = threadIdx.x >> 6;
  const int col = lane & 15, kg = lane >> 4;
  const float c2 = hc[col], c3 = hc[16 + col], c4 = hc[32 + col], c5 = hc[48 + col];
  const float Sg1 = sconst[0], Sb1 = sconst[1], Sbbc = sconst[2];
  const float Sgbc = sconst[3], Sggc = sconst[4];
  const h2 one = {(_Float16)1.f, (_Float16)1.f};
  const int sh = (col & 1) * 16;
  f32x4 accpv[16];
#pragma unroll
  for (int c = 0; c < 16; c++) accpv[c] = (f32x4){0.f, 0.f, 0.f, 0.f};
  float dh0 = 0.f, dh1 = 0.f, dh2 = 0.f, dh3 = 0.f;
  const int rbase = blockIdx.x * (16 * niter);
#pragma unroll 1
  for (int it = 0; it < niter; it++) {
    const int r0 = rbase + it * 16;
    const float* xrow = x + (size_t)(r0 + col) * D + w * 256 + kg * 8;
    f32x4 sacc = {0.f, 0.f, 0.f, 0.f};
    float S0 = 0, S1 = 0, Sa = 0, Sb = 0, Sc = 0, Sd = 0;
#pragma unroll
    for (int ks = 0; ks < 8; ks++) {
      const float4 A0 = *(const float4*)(xrow + ks * 32);
      const float4 A1 = *(const float4*)(xrow + ks * 32 + 4);
      const h2 a0 = pkh(A0.x, A0.y), a1 = pkh(A0.z, A0.w);
      const h2 a2 = pkh(A1.x, A1.y), a3 = pkh(A1.z, A1.w);
      const int gidx = (w * 8 + ks) * 4 + kg;
      const uint4 bu = sB[gidx * 16 + col];
      const uint4 gu = sg[gidx], g2u = sg2[gidx], gbu = sgb[gidx];
      S0 = fdot2(a0, one, S0); S0 = fdot2(a1, one, S0);
      S0 = fdot2(a2, one, S0); S0 = fdot2(a3, one, S0);
      S1 = fdot2(a0, a0, S1); S1 = fdot2(a1, a1, S1);
      S1 = fdot2(a2, a2, S1); S1 = fdot2(a3, a3, S1);
      const h2 g0 = bch(gu.x), g1p = bch(gu.y), g2p = bch(gu.z), g3p = bch(gu.w);
      Sa = fdot2(g0, a0, Sa); Sa = fdot2(g1p, a1, Sa);
      Sa = fdot2(g2p, a2, Sa); Sa = fdot2(g3p, a3, Sa);
      const h2 G0 = bch(g2u.x), G1 = bch(g2u.y), G2 = bch(g2u.z), G3 = bch(g2u.w);
      Sb = fdot2(G0, a0, Sb); Sb = fdot2(G1, a1, Sb);
      Sb = fdot2(G2, a2, Sb); Sb = fdot2(G3, a3, Sb);
      Sc = fdot2(G0, a0 * a0, Sc); Sc = fdot2(G1, a1 * a1, Sc);
      Sc = fdot2(G2, a2 * a2, Sc); Sc = fdot2(G3, a3 * a3, Sc);
      const h2 Q0 = bch(gbu.x), Q1 = bch(gbu.y), Q2 = bch(gbu.z), Q3 = bch(gbu.w);
      Sd = fdot2(Q0, a0, Sd); Sd = fdot2(Q1, a1, Sd);
      Sd = fdot2(Q2, a2, Sd); Sd = fdot2(Q3, a3, Sd);
      union { h2 p[4]; half8 v; } ua;
      ua.p[0] = a0; ua.p[1] = a1; ua.p[2] = a2; ua.p[3] = a3;
      sacc = __builtin_amdgcn_mfma_f32_16x16x32_f16(
          ua.v, __builtin_bit_cast(half8, bu), sacc, 0, 0, 0);
      uint4 xw;
      xw.x = hbits(a0); xw.y = hbits(a1); xw.z = hbits(a2); xw.w = hbits(a3);
      *(uint4*)&xl[w][col * 133 + kg * 4 + ks * 16] = xw;
    }
#pragma unroll
    for (int m = 16; m < 64; m <<= 1) {
      S0 += __shfl_xor(S0, m, 64); S1 += __shfl_xor(S1, m, 64);
      Sa += __shfl_xor(Sa, m, 64); Sb += __shfl_xor(Sb, m, 64);
      Sc += __shfl_xor(Sc, m, 64); Sd += __shfl_xor(Sd, m, 64);
    }
    if (lane < 16) {
      stat[w][lane][0] = S0; stat[w][lane][1] = S1; stat[w][lane][2] = Sa;
      stat[w][lane][3] = Sb; stat[w][lane][4] = Sc; stat[w][lane][5] = Sd;
    }
    sred[w][lane] = sacc;
    __syncthreads();
    f32x4 full = sred[0][lane];
    full += sred[1][lane]; full += sred[2][lane]; full += sred[3][lane];
    float T0 = 0, T1v = 0, Ta = 0, Tb = 0, Tc = 0, Td = 0;
#pragma unroll
    for (int ww = 0; ww < 4; ww++) {
      T0 += stat[ww][col][0]; T1v += stat[ww][col][1]; Ta += stat[ww][col][2];
      Tb += stat[ww][col][3]; Tc += stat[ww][col][4]; Td += stat[ww][col][5];
    }
    const float m1 = T0 * (1.f / D);
    const float rs1 = rsqrtf(T1v * (1.f / D) - m1 * m1 + EPS_LN);
    const float m2 = (rs1 * (Ta - m1 * Sg1) + Sb1) * (1.f / D);
    const float sxn2 = rs1 * rs1 * Tc + 2.f * rs1 * (Td - m1 * rs1 * Tb) +
                       (Sbbc - 2.f * m1 * rs1 * Sgbc + m1 * m1 * rs1 * rs1 * Sggc);
    const float rs2 = rsqrtf(sxn2 * (1.f / D) - m2 * m2 + EPS_LN);
    const float v1 = rs1 * rs2, v2 = v1 * m1, v3 = rs2, v4 = rs2 * m2;
    float ap_[4];
#pragma unroll
    for (int j = 0; j < 4; j++) {
      const int rj = kg * 4 + j;
      const float w1 = __shfl(v1, rj, 64), w2 = __shfl(v2, rj, 64);
      const float w3 = __shfl(v3, rj, 64), w4 = __shfl(v4, rj, 64);
      const float s = w1 * full[j] - w2 * c3 + w3 * c2 - w4 * c4 + c5;
      const float e = __expf(s);
      ap_[j] = e * w1;
      if (w == 0) { dh0 += e; dh1 += e * w3; dh2 += e * w2; dh3 += e * w4; }
    }
    union { h2 p[4]; half8 v; } ap;
    ap.p[0] = pkh(ap_[0], ap_[1]); ap.p[1] = pkh(ap_[2], ap_[3]);
    ap.p[2] = bch(0u); ap.p[3] = bch(0u);
    const unsigned int* xw = xl[w];
#pragma unroll
    for (int c = 0; c < 16; c++) {
      const int bidx = c * 8 + (col >> 1);
      const unsigned int r0w = xw[(kg * 4 + 0) * 133 + bidx];
      const unsigned int r1w = xw[(kg * 4 + 1) * 133 + bidx];
      const unsigned int r2w = xw[(kg * 4 + 2) * 133 + bidx];
      const unsigned int r3w = xw[(kg * 4 + 3) * 133 + bidx];
      union { unsigned int u[4]; half8 v; } bb;
      bb.u[0] = ((r0w >> sh) & 0xffffu) | (((r1w >> sh) & 0xffffu) << 16);
      bb.u[1] = ((r2w >> sh) & 0xffffu) | (((r3w >> sh) & 0xffffu) << 16);
      bb.u[2] = 0u; bb.u[3] = 0u;
      accpv[c] = __builtin_amdgcn_mfma_f32_16x16x32_f16(ap.v, bb.v, accpv[c], 0, 0, 0);
    }
    __syncthreads();
  }
  if (w == 0) {
#pragma unroll
    for (int m = 16; m < 64; m <<= 1) {
      dh0 += __shfl_xor(dh0, m, 64); dh1 += __shfl_xor(dh1, m, 64);
      dh2 += __shfl_xor(dh2, m, 64); dh3 += __shfl_xor(dh3, m, 64);
    }
    if (lane < 16) {
      const int b = blockIdx.x / bpb;
      float* cb = Cbuf + (b * 16 + lane) * 4;
      atomicAdd(cb + 0, dh0); atomicAdd(cb + 1, dh1);
      atomicAdd(cb + 2, dh2); atomicAdd(cb + 3, dh3);
    }
  }
  float* po = part + ((size_t)blockIdx.x * 16) * 1024 + w * 256;
#pragma unroll
  for (int c = 0; c < 16; c++) {
#pragma unroll
    for (int reg = 0; reg < 4; reg++) {
      const int h = kg * 4 + reg;
      po[(size_t)h * 1024 + c * 16 + col] = accpv[c][reg];
    }
  }
}

// ---------- reduce partials + normalize + affine V-input assembly ----------
__global__ void k_reduce(const float* __restrict__ part, const float* __restrict__ Cbuf,
                         const float* __restrict__ g1, const float* __restrict__ b1,
                         const float* __restrict__ vg, const float* __restrict__ vb,
                         float* __restrict__ vpool, int bpb) {
  const int b = blockIdx.x >> 4, h = blockIdx.x & 15;
  const int t = threadIdx.x, d = t * 4;
  float4 a = make_float4(0.f, 0.f, 0.f, 0.f);
  for (int k = 0; k < bpb; k++) {
    const float4 p =
        *(const float4*)(part + ((size_t)((b * bpb + k) * 16 + h)) * 1024 + d);
    a.x += p.x; a.y += p.y; a.z += p.z; a.w += p.w;
  }
  const float4 C = ((const float4*)Cbuf)[b * 16 + h];  // den, C1, C2, C3 (unnorm)
  const float inv = 1.f / C.x;
  const float C1n = C.y * inv, C2n = C.z * inv, C3n = C.w * inv;
  const float4 gv = ((const float4*)g1)[t], bv = ((const float4*)b1)[t];
  const float4 vgv = ((const float4*)vg)[t], vbv = ((const float4*)vb)[t];
  float4 o;
  o.x = vgv.x * (gv.x * (a.x * inv - C2n) + bv.x * C1n - C3n) + vbv.x;
  o.y = vgv.y * (gv.y * (a.y * inv - C2n) + bv.y * C1n - C3n) + vbv.y;
  o.z = vgv.z * (gv.z * (a.z * inv - C2n) + bv.z * C1n - C3n) + vbv.z;
  o.w = vgv.w * (gv.w * (a.w * inv - C2n) + bv.w * C1n - C3n) + vbv.w;
  *(float4*)(vpool + ((size_t)b * H + h) * D + d) = o;
}

// ---------- out[b][j] = W[j,:] . src[b, head-sliced] + bias[j] ----------
__global__ void k_proj8(const float* __restrict__ src, const float* __restrict__ W,
                        const float* __restrict__ bias, float* __restrict__ out,
                        int bstride, int hstride) {
  const int j = blockIdx.x, lane = threadIdx.x;
  const int h = j >> 6;
  const float4* wr = (const float4*)(W + (size_t)j * D);
  float acc[8];
#pragma unroll
  for (int b = 0; b < 8; b++) acc[b] = 0.f;
#pragma unroll
  for (int k = 0; k < 4; k++) {
    const float4 w4 = wr[lane + 64 * k];
#pragma unroll
    for (int b = 0; b < 8; b++) {
      const float4 s4 =
          ((const float4*)(src + (size_t)b * bstride + (size_t)h * hstride))[lane + 64 * k];
      acc[b] = fmaf(w4.x, s4.x, acc[b]); acc[b] = fmaf(w4.y, s4.y, acc[b]);
      acc[b] = fmaf(w4.z, s4.z, acc[b]); acc[b] = fmaf(w4.w, s4.w, acc[b]);
    }
  }
#pragma unroll
  for (int b = 0; b < 8; b++) acc[b] = wred_sum(acc[b]);
  if (!lane) {
    const float bj = bias[j];
#pragma unroll
    for (int b = 0; b < 8; b++) out[(size_t)b * D + j] = acc[b] + bj;
  }
}

extern "C" void kernel_launch(void* const* d_in, const int* in_sizes, int n_in,
                              void* d_out, int out_size, void* d_ws, size_t ws_size,
                              hipStream_t stream) {
  const float* x = (const float*)d_in[0];
  const float* query = (const float*)d_in[1];
  const float* norm_g = (const float*)d_in[2];
  const float* norm_b = (const float*)d_in[3];
  const float* nq_g = (const float*)d_in[4];
  const float* nq_b = (const float*)d_in[5];
  const float* nk_g = (const float*)d_in[6];
  const float* nk_b = (const float*)d_in[7];
  const float* nv_g = (const float*)d_in[8];
  const float* nv_b = (const float*)d_in[9];
  const float* no_g = (const float*)d_in[10];
  const float* no_b = (const float*)d_in[11];
  const float* Wq = (const float*)d_in[12];
  const float* bq = (const float*)d_in[13];
  const float* Wk = (const float*)d_in[14];
  // d_in[15] = bk: constant per (b,h) in scores -> cancels in softmax
  const float* Wv = (const float*)d_in[16];
  const float* bv = (const float*)d_in[17];
  const float* Wo = (const float*)d_in[18];
  const float* bo = (const float*)d_in[19];

  char* ws = (char*)d_ws;
  float* qv = (float*)(ws + 0);           // 4 KB
  uint4* B1 = (uint4*)(ws + 4096);        // 32 KB
  uint4* gt = (uint4*)(ws + 36864);       // 2 KB
  uint4* g2t = (uint4*)(ws + 38912);      // 2 KB
  uint4* gbt = (uint4*)(ws + 40960);      // 2 KB
  float* hc = (float*)(ws + 43008);       // 256 B
  float* sconst = (float*)(ws + 43264);   // 64 B
  float* Cbuf = (float*)(ws + 43328);     // 2 KB
  float* vpool = (float*)(ws + 45568);    // 512 KB
  float* av = (float*)(ws + 569856);      // 32 KB
  float* yb = (float*)(ws + 602624);      // 32 KB
  float* part = (float*)(ws + 635904);    // NBLK*16*1024*4

  int NBLK = 512;
  if (635904ull + (size_t)NBLK * 16 * 1024 * 4 > ws_size) NBLK = 256;
  const int niter = NROWS / (16 * NBLK);
  const int bpb = NBLK / B;

  k_qln<<<256, 256, 0, stream>>>(query, nq_g, nq_b, Wq, bq, qv);
  k_prep0G<<<1, 256, 0, stream>>>(norm_g, norm_b, sconst, gt, g2t, gbt, hc, Cbuf);
  k_uprep64<<<64, 256, 0, stream>>>(qv, Wk, norm_g, norm_b, nk_g, nk_b, hc, B1);
  k_fused<<<NBLK, 256, 0, stream>>>(x, B1, gt, g2t, gbt, hc, sconst, part, Cbuf,
                                    niter, bpb);
  k_reduce<<<128, 256, 0, stream>>>(part, Cbuf, norm_g, norm_b, nv_g, nv_b, vpool, bpb);
  k_proj8<<<1024, 64, 0, stream>>>(vpool, Wv, bv, av, H * D, D);  // V-proj on pooled
  k_proj8<<<1024, 64, 0, stream>>>(av, Wo, bo, yb, D, 0);         // O-proj
  k_ln256<<<8, 256, 0, stream>>>(yb, no_g, no_b, (float*)d_out);
}